// Round 1
// baseline (484.136 us; speedup 1.0000x reference)
//
#include <hip/hip_runtime.h>

#define NN 8192
#define INF 128
#define OUTF 64
#define KK 2
#define NROWS (KK * NN)
#define MAXD_LDS 1024
#define MAXD_CSR 256
#define WH_RPB 16

// ---------------- Kernel 1: Wh = x@W, Wh1 = Wh@a[:64], Wh2 = Wh@a[64:] -------
__global__ __launch_bounds__(256) void wh_kernel(
    const float* __restrict__ x, const float* __restrict__ weight,
    const float* __restrict__ a,
    float* __restrict__ Wh, float* __restrict__ Wh1, float* __restrict__ Wh2)
{
    __shared__ float sW[INF * OUTF];       // 32 KB
    __shared__ float sx[WH_RPB * INF];     // 8 KB
    int tid = threadIdx.x;
    for (int idx = tid; idx < INF * OUTF; idx += 256) sW[idx] = weight[idx];
    long long rowBase = (long long)blockIdx.x * WH_RPB;   // global row in [0, 16384)
    const float* xb = x + rowBase * INF;
    for (int idx = tid; idx < WH_RPB * INF; idx += 256) sx[idx] = xb[idx];
    __syncthreads();

    int wave = tid >> 6, lane = tid & 63;
    float a1 = a[lane], a2 = a[OUTF + lane];
    for (int r = wave; r < WH_RPB; r += 4) {
        float acc = 0.f;
#pragma unroll 8
        for (int c = 0; c < INF; ++c) acc += sx[r * INF + c] * sW[c * OUTF + lane];
        long long row = rowBase + r;
        Wh[row * OUTF + lane] = acc;
        float w1 = acc * a1, w2 = acc * a2;
#pragma unroll
        for (int off = 32; off; off >>= 1) {
            w1 += __shfl_down(w1, off);
            w2 += __shfl_down(w2, off);
        }
        if (lane == 0) { Wh1[row] = w1; Wh2[row] = w2; }
    }
}

// ---------------- Kernel 2: sparse masked softmax + att@Wh, builds CSR -------
__global__ __launch_bounds__(256) void attn_kernel(
    const float* __restrict__ adj,
    const float* __restrict__ Wh, const float* __restrict__ Wh1,
    const float* __restrict__ Wh2,
    float* __restrict__ h_prime, int* __restrict__ deg, int* __restrict__ nbrs,
    int use_csr)
{
    __shared__ int   s_idx[MAXD_LDS];     // 4 KB
    __shared__ float s_p0[MAXD_LDS];      // 4 KB
    __shared__ float s_p1[MAXD_LDS];      // 4 KB
    __shared__ float s_red0[4], s_red1[4];
    __shared__ float s_m0, s_m1, s_s0, s_s1;
    __shared__ int   s_cnt;
    __shared__ float s_acc[2 * 128];      // 1 KB

    int tid = threadIdx.x;
    int i = blockIdx.x;
    if (tid == 0) s_cnt = 0;
    __syncthreads();

    // Phase A: scan adjacency row, collect neighbor indices
    const float4* row4 = (const float4*)(adj + (long long)i * NN);
#pragma unroll
    for (int it = 0; it < NN / (4 * 256); ++it) {
        int q4 = tid + it * 256;
        float4 v = row4[q4];
        int q = q4 * 4;
        if (v.x > 0.f) { int p = atomicAdd(&s_cnt, 1); if (p < MAXD_LDS) s_idx[p] = q; }
        if (v.y > 0.f) { int p = atomicAdd(&s_cnt, 1); if (p < MAXD_LDS) s_idx[p] = q + 1; }
        if (v.z > 0.f) { int p = atomicAdd(&s_cnt, 1); if (p < MAXD_LDS) s_idx[p] = q + 2; }
        if (v.w > 0.f) { int p = atomicAdd(&s_cnt, 1); if (p < MAXD_LDS) s_idx[p] = q + 3; }
    }
    __syncthreads();
    int d = s_cnt; if (d > MAXD_LDS) d = MAXD_LDS;

    // Persist CSR for the second aggregation kernel
    if (use_csr) {
        if (tid == 0) deg[i] = d;
        if (d <= MAXD_CSR) {
            for (int t = tid; t < d; t += 256)
                nbrs[(long long)i * MAXD_CSR + t] = s_idx[t];
        }
    }

    // Phase B: e = relu(Wh1_i + Wh2_j) over neighbors, exact softmax (both k)
    float wh1_0 = Wh1[i];
    float wh1_1 = Wh1[NN + i];
    float m0 = -1e30f, m1 = -1e30f;
    for (int t = tid; t < d; t += 256) {
        int j = s_idx[t];
        float e0 = fmaxf(wh1_0 + Wh2[j], 0.f);
        float e1 = fmaxf(wh1_1 + Wh2[NN + j], 0.f);
        s_p0[t] = e0; s_p1[t] = e1;
        m0 = fmaxf(m0, e0); m1 = fmaxf(m1, e1);
    }
#pragma unroll
    for (int off = 32; off; off >>= 1) {
        m0 = fmaxf(m0, __shfl_down(m0, off));
        m1 = fmaxf(m1, __shfl_down(m1, off));
    }
    int lane = tid & 63, wv = tid >> 6;
    if (lane == 0) { s_red0[wv] = m0; s_red1[wv] = m1; }
    __syncthreads();
    if (tid == 0) {
        float t0 = s_red0[0], t1 = s_red1[0];
        for (int w = 1; w < 4; ++w) { t0 = fmaxf(t0, s_red0[w]); t1 = fmaxf(t1, s_red1[w]); }
        s_m0 = t0; s_m1 = t1;
    }
    __syncthreads();
    m0 = s_m0; m1 = s_m1;
    float sum0 = 0.f, sum1 = 0.f;
    for (int t = tid; t < d; t += 256) {
        float p0 = expf(s_p0[t] - m0);
        float p1 = expf(s_p1[t] - m1);
        s_p0[t] = p0; s_p1[t] = p1;
        sum0 += p0; sum1 += p1;
    }
    __syncthreads();
#pragma unroll
    for (int off = 32; off; off >>= 1) {
        sum0 += __shfl_down(sum0, off);
        sum1 += __shfl_down(sum1, off);
    }
    if (lane == 0) { s_red0[wv] = sum0; s_red1[wv] = sum1; }
    __syncthreads();
    if (tid == 0) {
        float t0 = 0.f, t1 = 0.f;
        for (int w = 0; w < 4; ++w) { t0 += s_red0[w]; t1 += s_red1[w]; }
        s_s0 = t0; s_s1 = t1;
    }
    __syncthreads();
    float inv0 = s_s0 > 0.f ? 1.f / s_s0 : 0.f;
    float inv1 = s_s1 > 0.f ? 1.f / s_s1 : 0.f;

    // Phase C: h_prime[k,i,:] = sum_t p[k][t] * Wh[k, j_t, :]
    // 256 threads = 2 halves x (2 k x 64 f)
    int half = tid >> 7;
    int kf = tid & 127;
    int k = kf >> 6, f = kf & 63;
    const float* WhK = Wh + (long long)k * NN * OUTF;
    const float* pk = (k == 0) ? s_p0 : s_p1;
    float acc = 0.f;
    for (int t = half; t < d; t += 2)
        acc += pk[t] * WhK[(long long)s_idx[t] * OUTF + f];
    s_acc[half * 128 + kf] = acc;
    __syncthreads();
    if (tid < 128) {
        int k2 = tid >> 6, f2 = tid & 63;
        float v = s_acc[tid] + s_acc[128 + tid];
        float inv = (k2 == 0) ? inv0 : inv1;
        h_prime[((long long)k2 * NN + i) * OUTF + f2] = v * inv;
    }
}

// ---------------- Kernel 3: out = relu(adj @ h_prime), via CSR ----------------
__global__ __launch_bounds__(256) void spmm_kernel(
    const float* __restrict__ adj, const float* __restrict__ h_prime,
    const int* __restrict__ deg, const int* __restrict__ nbrs,
    float* __restrict__ out, int use_csr)
{
    __shared__ int   s_idx[MAXD_LDS];
    __shared__ int   s_cnt;
    __shared__ float s_acc[2 * 128];
    int tid = threadIdx.x;
    int i = blockIdx.x;
    int d = 0;
    bool from_csr = false;
    if (use_csr) {
        d = deg[i];                        // block-uniform
        if (d <= MAXD_CSR) from_csr = true;
    }
    if (from_csr) {
        for (int t = tid; t < d; t += 256)
            s_idx[t] = nbrs[(long long)i * MAXD_CSR + t];
    } else {
        if (tid == 0) s_cnt = 0;
        __syncthreads();
        const float4* row4 = (const float4*)(adj + (long long)i * NN);
#pragma unroll
        for (int it = 0; it < NN / (4 * 256); ++it) {
            int q4 = tid + it * 256;
            float4 v = row4[q4];
            int q = q4 * 4;
            if (v.x > 0.f) { int p = atomicAdd(&s_cnt, 1); if (p < MAXD_LDS) s_idx[p] = q; }
            if (v.y > 0.f) { int p = atomicAdd(&s_cnt, 1); if (p < MAXD_LDS) s_idx[p] = q + 1; }
            if (v.z > 0.f) { int p = atomicAdd(&s_cnt, 1); if (p < MAXD_LDS) s_idx[p] = q + 2; }
            if (v.w > 0.f) { int p = atomicAdd(&s_cnt, 1); if (p < MAXD_LDS) s_idx[p] = q + 3; }
        }
        __syncthreads();
        d = s_cnt; if (d > MAXD_LDS) d = MAXD_LDS;
    }
    __syncthreads();

    int half = tid >> 7, kf = tid & 127, k = kf >> 6, f = kf & 63;
    const float* hK = h_prime + (long long)k * NN * OUTF;
    float acc = 0.f;
    for (int t = half; t < d; t += 2)
        acc += hK[(long long)s_idx[t] * OUTF + f];
    s_acc[half * 128 + kf] = acc;
    __syncthreads();
    if (tid < 128) {
        int k2 = tid >> 6, f2 = tid & 63;
        float v = s_acc[tid] + s_acc[128 + tid];
        out[((long long)k2 * NN + i) * OUTF + f2] = fmaxf(v, 0.f);
    }
}

extern "C" void kernel_launch(void* const* d_in, const int* in_sizes, int n_in,
                              void* d_out, int out_size, void* d_ws, size_t ws_size,
                              hipStream_t stream) {
    const float* x      = (const float*)d_in[0];   // [2, 8192, 128]
    const float* adj    = (const float*)d_in[1];   // [8192, 8192]
    const float* weight = (const float*)d_in[2];   // [128, 64]
    const float* a      = (const float*)d_in[3];   // [128, 1]
    float* out = (float*)d_out;                    // [2, 8192, 64]

    // workspace layout (floats/ints, 4 B each)
    float* Wh      = (float*)d_ws;                 // 16384*64
    float* Wh1     = Wh + (size_t)NROWS * OUTF;    // 16384
    float* Wh2     = Wh1 + NROWS;                  // 16384
    float* h_prime = Wh2 + NROWS;                  // 16384*64
    int*   deg     = (int*)(h_prime + (size_t)NROWS * OUTF);  // 8192
    int*   nbrs    = deg + NN;                     // 8192*256

    size_t need_csr = ((size_t)NROWS * OUTF * 2 + (size_t)NROWS * 2 + NN
                       + (size_t)NN * MAXD_CSR) * 4;
    int use_csr = (ws_size >= need_csr) ? 1 : 0;

    wh_kernel<<<NROWS / WH_RPB, 256, 0, stream>>>(x, weight, a, Wh, Wh1, Wh2);
    attn_kernel<<<NN, 256, 0, stream>>>(adj, Wh, Wh1, Wh2, h_prime, deg, nbrs, use_csr);
    spmm_kernel<<<NN, 256, 0, stream>>>(adj, h_prime, deg, nbrs, out, use_csr);
}

// Round 2
// 428.294 us; speedup vs baseline: 1.1304x; 1.1304x over previous
//
#include <hip/hip_runtime.h>

#define NN 8192
#define INF 128
#define OUTF 64
#define KK 2
#define NROWS (KK * NN)
#define MAXD 256
#define WH_RPB 16

// ---------------- Kernel 1: Wh = x@W (interleaved [j][k][f]), Wh1, W2I -------
__global__ __launch_bounds__(256) void wh_kernel(
    const float* __restrict__ x, const float* __restrict__ weight,
    const float* __restrict__ a,
    float* __restrict__ WhI, float* __restrict__ Wh1, float* __restrict__ W2I)
{
    __shared__ float sW[INF * OUTF];       // 32 KB
    __shared__ float sx[WH_RPB * INF];     // 8 KB
    int tid = threadIdx.x;
    for (int idx = tid; idx < INF * OUTF; idx += 256) sW[idx] = weight[idx];
    int rowBase = blockIdx.x * WH_RPB;     // global row in [0, 16384)
    const float* xb = x + (size_t)rowBase * INF;
    for (int idx = tid; idx < WH_RPB * INF; idx += 256) sx[idx] = xb[idx];
    __syncthreads();

    int wave = tid >> 6, lane = tid & 63;
    float a1 = a[lane], a2 = a[OUTF + lane];
    for (int r = wave; r < WH_RPB; r += 4) {
        float acc = 0.f;
#pragma unroll 16
        for (int c = 0; c < INF; ++c) acc += sx[r * INF + c] * sW[c * OUTF + lane];
        int g = rowBase + r;
        int k = g >> 13;                   // g / NN
        int j = g & (NN - 1);              // g % NN
        WhI[((size_t)j * KK + k) * OUTF + lane] = acc;
        float w1 = acc * a1, w2 = acc * a2;
#pragma unroll
        for (int off = 32; off; off >>= 1) {
            w1 += __shfl_down(w1, off);
            w2 += __shfl_down(w2, off);
        }
        if (lane == 0) { Wh1[k * NN + j] = w1; W2I[j * KK + k] = w2; }
    }
}

// ------- Kernel 2: scan adj row (ballot compact) + sparse softmax + att@Wh ---
__global__ __launch_bounds__(256) void attn_kernel(
    const float* __restrict__ adj, const float* __restrict__ WhI,
    const float* __restrict__ Wh1, const float* __restrict__ W2I,
    float* __restrict__ hI, int* __restrict__ deg, int* __restrict__ nbrs)
{
    __shared__ int   s_idx[MAXD];          // 1 KB
    __shared__ float s_p0[MAXD], s_p1[MAXD]; // 2 KB
    __shared__ float s_r0[4], s_r1[4];
    __shared__ int   s_cnt;
    __shared__ float s_acc[256];           // 1 KB

    int tid = threadIdx.x;
    int i = blockIdx.x;
    int lane = tid & 63, wv = tid >> 6;
    if (tid == 0) s_cnt = 0;
    __syncthreads();

    // ---- Phase A: scan adjacency row, ballot-compact neighbor indices ----
    const float4* row4 = (const float4*)(adj + (size_t)i * NN);
    unsigned long long lmask = (1ull << lane) - 1ull;
#pragma unroll
    for (int it = 0; it < NN / (4 * 256); ++it) {
        int q4 = tid + it * 256;
        float4 v = row4[q4];
        int q = q4 * 4;
        float comp[4] = {v.x, v.y, v.z, v.w};
#pragma unroll
        for (int c = 0; c < 4; ++c) {
            bool pr = comp[c] > 0.f;
            unsigned long long m = __ballot(pr);
            if (m) {                       // wave-uniform branch
                int base;
                if (lane == 0) base = atomicAdd(&s_cnt, __popcll(m));
                base = __shfl(base, 0);
                if (pr) {
                    int pos = base + __popcll(m & lmask);
                    if (pos < MAXD) s_idx[pos] = q + c;
                }
            }
        }
    }
    __syncthreads();
    int d = min(s_cnt, MAXD);
    if (tid == 0) deg[i] = d;
    if (tid < d) nbrs[(size_t)i * MAXD + tid] = s_idx[tid];

    // ---- Phase B: e = relu(Wh1_i + Wh2_j), exact softmax (one thread per nbr)
    float wh1_0 = Wh1[i];
    float wh1_1 = Wh1[NN + i];
    float e0 = -1e30f, e1 = -1e30f;
    if (tid < d) {
        int j = s_idx[tid];
        float2 w2 = ((const float2*)W2I)[j];
        e0 = fmaxf(wh1_0 + w2.x, 0.f);
        e1 = fmaxf(wh1_1 + w2.y, 0.f);
    }
    float m0 = e0, m1 = e1;
#pragma unroll
    for (int off = 32; off; off >>= 1) {
        m0 = fmaxf(m0, __shfl_down(m0, off));
        m1 = fmaxf(m1, __shfl_down(m1, off));
    }
    if (lane == 0) { s_r0[wv] = m0; s_r1[wv] = m1; }
    __syncthreads();
    m0 = fmaxf(fmaxf(s_r0[0], s_r0[1]), fmaxf(s_r0[2], s_r0[3]));
    m1 = fmaxf(fmaxf(s_r1[0], s_r1[1]), fmaxf(s_r1[2], s_r1[3]));
    __syncthreads();                       // s_r reuse below
    float p0 = 0.f, p1 = 0.f;
    if (tid < d) {
        p0 = __expf(e0 - m0);
        p1 = __expf(e1 - m1);
        s_p0[tid] = p0; s_p1[tid] = p1;
    }
    float t0 = p0, t1 = p1;
#pragma unroll
    for (int off = 32; off; off >>= 1) {
        t0 += __shfl_down(t0, off);
        t1 += __shfl_down(t1, off);
    }
    if (lane == 0) { s_r0[wv] = t0; s_r1[wv] = t1; }
    __syncthreads();
    float sum0 = s_r0[0] + s_r0[1] + s_r0[2] + s_r0[3];
    float sum1 = s_r1[0] + s_r1[1] + s_r1[2] + s_r1[3];
    float inv0 = sum0 > 0.f ? 1.f / sum0 : 0.f;
    float inv1 = sum1 > 0.f ? 1.f / sum1 : 0.f;

    // ---- Phase C: h'[i,k,f] = sum_t p[k][t] * Wh[j_t,k,f]  (unroll-4 gather)
    int half = tid >> 7;                   // 2 halves split the t-range
    int kf = tid & 127;                    // k*64 + f
    int k = kf >> 6;
    const float* pk = k ? s_p1 : s_p0;
    const float* Wb = WhI + kf;
    float acc = 0.f;
    int t = half;
    for (; t + 6 < d; t += 8) {
        int j0 = s_idx[t], j1 = s_idx[t + 2], j2 = s_idx[t + 4], j3 = s_idx[t + 6];
        float a0 = pk[t], a1 = pk[t + 2], a2 = pk[t + 4], a3 = pk[t + 6];
        float v0 = Wb[(size_t)j0 * 128], v1 = Wb[(size_t)j1 * 128];
        float v2 = Wb[(size_t)j2 * 128], v3 = Wb[(size_t)j3 * 128];
        acc += a0 * v0 + a1 * v1 + a2 * v2 + a3 * v3;
    }
    for (; t < d; t += 2) acc += pk[t] * Wb[(size_t)s_idx[t] * 128];
    s_acc[tid] = acc;
    __syncthreads();
    if (tid < 128) {
        float v = s_acc[tid] + s_acc[128 + tid];
        float inv = (tid >= 64) ? inv1 : inv0;
        hI[(size_t)i * 128 + tid] = v * inv;  // [i][k][f] interleaved
    }
}

// ---------------- Kernel 3: out = relu(adj @ h'), via CSR (unroll-4 gather) --
__global__ __launch_bounds__(256) void spmm_kernel(
    const float* __restrict__ hI, const int* __restrict__ deg,
    const int* __restrict__ nbrs, float* __restrict__ out)
{
    __shared__ int   s_idx[MAXD];
    __shared__ float s_acc[256];
    int tid = threadIdx.x, i = blockIdx.x;
    int d = deg[i];
    if (tid < d) s_idx[tid] = nbrs[(size_t)i * MAXD + tid];
    __syncthreads();

    int half = tid >> 7, kf = tid & 127;
    const float* hb = hI + kf;
    float acc = 0.f;
    int t = half;
    for (; t + 6 < d; t += 8) {
        int j0 = s_idx[t], j1 = s_idx[t + 2], j2 = s_idx[t + 4], j3 = s_idx[t + 6];
        acc += hb[(size_t)j0 * 128] + hb[(size_t)j1 * 128]
             + hb[(size_t)j2 * 128] + hb[(size_t)j3 * 128];
    }
    for (; t < d; t += 2) acc += hb[(size_t)s_idx[t] * 128];
    s_acc[tid] = acc;
    __syncthreads();
    if (tid < 128) {
        int k = tid >> 6, f = tid & 63;
        float v = s_acc[tid] + s_acc[128 + tid];
        out[((size_t)k * NN + i) * OUTF + f] = fmaxf(v, 0.f);
    }
}

extern "C" void kernel_launch(void* const* d_in, const int* in_sizes, int n_in,
                              void* d_out, int out_size, void* d_ws, size_t ws_size,
                              hipStream_t stream) {
    const float* x      = (const float*)d_in[0];   // [2, 8192, 128]
    const float* adj    = (const float*)d_in[1];   // [8192, 8192]
    const float* weight = (const float*)d_in[2];   // [128, 64]
    const float* a      = (const float*)d_in[3];   // [128, 1]
    float* out = (float*)d_out;                    // [2, 8192, 64]

    // workspace layout (4 B elems): WhI [N][2][64] | Wh1 [2][N] | W2I [N][2]
    //                               hI [N][2][64] | deg [N] | nbrs [N][MAXD]
    float* WhI = (float*)d_ws;
    float* Wh1 = WhI + (size_t)NN * KK * OUTF;
    float* W2I = Wh1 + NROWS;
    float* hI  = W2I + (size_t)NN * KK;
    int*   deg = (int*)(hI + (size_t)NN * KK * OUTF);
    int*   nbrs = deg + NN;

    wh_kernel<<<NROWS / WH_RPB, 256, 0, stream>>>(x, weight, a, WhI, Wh1, W2I);
    attn_kernel<<<NN, 256, 0, stream>>>(adj, WhI, Wh1, W2I, hI, deg, nbrs);
    spmm_kernel<<<NN, 256, 0, stream>>>(hI, deg, nbrs, out);
}

// Round 3
// 409.725 us; speedup vs baseline: 1.1816x; 1.0453x over previous
//
#include <hip/hip_runtime.h>
#include <hip/hip_fp16.h>

#define NN 8192
#define INF 128
#define OUTF 64
#define KK 2
#define NROWS (KK * NN)
#define MAXD 256
#define WH_RPB 16

// ---- Kernel 1: Wh = x@W -> WhI fp16 [j][k*64+f]; Wh1 fp32 [k][N]; W2I fp32 [j][k]
__global__ __launch_bounds__(256) void wh_kernel(
    const float* __restrict__ x, const float* __restrict__ weight,
    const float* __restrict__ a,
    __half* __restrict__ WhI, float* __restrict__ Wh1, float* __restrict__ W2I)
{
    __shared__ float sW[INF * OUTF];       // 32 KB
    __shared__ float sx[WH_RPB * INF];     // 8 KB
    int tid = threadIdx.x;
#pragma unroll
    for (int idx = tid; idx < (INF * OUTF) / 4; idx += 256)
        ((float4*)sW)[idx] = ((const float4*)weight)[idx];
    int rowBase = blockIdx.x * WH_RPB;     // global row in [0, 16384)
    const float4* xb = (const float4*)(x + (size_t)rowBase * INF);
#pragma unroll
    for (int idx = tid; idx < (WH_RPB * INF) / 4; idx += 256)
        ((float4*)sx)[idx] = xb[idx];
    __syncthreads();

    int wave = tid >> 6, lane = tid & 63;
    float a1 = a[lane], a2 = a[OUTF + lane];
    for (int r = wave; r < WH_RPB; r += 4) {
        float acc = 0.f;
#pragma unroll 16
        for (int c = 0; c < INF; ++c) acc += sx[r * INF + c] * sW[c * OUTF + lane];
        int g = rowBase + r;
        int k = g >> 13;                   // g / NN
        int j = g & (NN - 1);              // g % NN
        WhI[(size_t)j * 128 + k * OUTF + lane] = __float2half(acc);
        float w1 = acc * a1, w2 = acc * a2;
#pragma unroll
        for (int off = 32; off; off >>= 1) {
            w1 += __shfl_down(w1, off);
            w2 += __shfl_down(w2, off);
        }
        if (lane == 0) { Wh1[k * NN + j] = w1; W2I[j * KK + k] = w2; }
    }
}

// ---- Kernel 2: adj-row scan (ballot compact) + sparse softmax + att@Wh -> hI fp16
__global__ __launch_bounds__(256) void attn_kernel(
    const float* __restrict__ adj, const __half* __restrict__ WhI,
    const float* __restrict__ Wh1, const float* __restrict__ W2I,
    __half* __restrict__ hI, int* __restrict__ deg, int* __restrict__ nbrs)
{
    __shared__ int   s_idx[MAXD];            // 1 KB
    __shared__ float s_p0[MAXD], s_p1[MAXD]; // 2 KB
    __shared__ float s_r0[4], s_r1[4];
    __shared__ int   s_cnt;
    __shared__ float2 s_acc[256];            // 2 KB

    int tid = threadIdx.x;
    int i = blockIdx.x;
    int lane = tid & 63, wv = tid >> 6;
    if (tid == 0) s_cnt = 0;
    __syncthreads();

    // ---- Phase A: scan adjacency row, ballot-compact neighbor indices ----
    const float4* row4 = (const float4*)(adj + (size_t)i * NN);
    unsigned long long lmask = (1ull << lane) - 1ull;
#pragma unroll
    for (int it = 0; it < NN / (4 * 256); ++it) {
        int q4 = tid + it * 256;
        float4 v = row4[q4];
        int q = q4 * 4;
        float comp[4] = {v.x, v.y, v.z, v.w};
#pragma unroll
        for (int c = 0; c < 4; ++c) {
            bool pr = comp[c] > 0.f;
            unsigned long long m = __ballot(pr);
            if (m) {                       // wave-uniform branch
                int base;
                if (lane == 0) base = atomicAdd(&s_cnt, __popcll(m));
                base = __shfl(base, 0);
                if (pr) {
                    int pos = base + __popcll(m & lmask);
                    if (pos < MAXD) s_idx[pos] = q + c;
                }
            }
        }
    }
    __syncthreads();
    int d = min(s_cnt, MAXD);
    if (tid == 0) deg[i] = d;
    if (tid < d) nbrs[(size_t)i * MAXD + tid] = s_idx[tid];

    // ---- Phase B: e = relu(Wh1_i + Wh2_j), exact softmax (one thread per nbr)
    float wh1_0 = Wh1[i];
    float wh1_1 = Wh1[NN + i];
    float e0 = -1e30f, e1 = -1e30f;
    if (tid < d) {
        int j = s_idx[tid];
        float2 w2 = ((const float2*)W2I)[j];
        e0 = fmaxf(wh1_0 + w2.x, 0.f);
        e1 = fmaxf(wh1_1 + w2.y, 0.f);
    }
    float m0 = e0, m1 = e1;
#pragma unroll
    for (int off = 32; off; off >>= 1) {
        m0 = fmaxf(m0, __shfl_down(m0, off));
        m1 = fmaxf(m1, __shfl_down(m1, off));
    }
    if (lane == 0) { s_r0[wv] = m0; s_r1[wv] = m1; }
    __syncthreads();
    m0 = fmaxf(fmaxf(s_r0[0], s_r0[1]), fmaxf(s_r0[2], s_r0[3]));
    m1 = fmaxf(fmaxf(s_r1[0], s_r1[1]), fmaxf(s_r1[2], s_r1[3]));
    __syncthreads();                       // WAR on s_r
    float p0 = 0.f, p1 = 0.f;
    if (tid < d) {
        p0 = __expf(e0 - m0);
        p1 = __expf(e1 - m1);
        s_p0[tid] = p0; s_p1[tid] = p1;
    }
    float t0 = p0, t1 = p1;
#pragma unroll
    for (int off = 32; off; off >>= 1) {
        t0 += __shfl_down(t0, off);
        t1 += __shfl_down(t1, off);
    }
    if (lane == 0) { s_r0[wv] = t0; s_r1[wv] = t1; }
    __syncthreads();
    float sum0 = s_r0[0] + s_r0[1] + s_r0[2] + s_r0[3];
    float sum1 = s_r1[0] + s_r1[1] + s_r1[2] + s_r1[3];
    float inv0 = sum0 > 0.f ? 1.f / sum0 : 0.f;
    float inv1 = sum1 > 0.f ? 1.f / sum1 : 0.f;

    // ---- Phase C: h'[i, 2h..2h+1] = sum_t p[k][t] * WhI[j_t, 2h..2h+1]
    // 256 threads = 4 groups x 64 half2-columns; fp16 gather, fp32 accumulate
    int grp = tid >> 6;                    // t-range split 4 ways
    int h = tid & 63;                      // half2 column; k = h>>5
    const float* pk = (h & 32) ? s_p1 : s_p0;
    const __half2* Wb = (const __half2*)WhI + h;
    float2 acc = {0.f, 0.f};
    int t = grp;
    for (; t + 12 < d; t += 16) {
        int j0 = s_idx[t], j1 = s_idx[t + 4], j2 = s_idx[t + 8], j3 = s_idx[t + 12];
        float q0 = pk[t], q1 = pk[t + 4], q2 = pk[t + 8], q3 = pk[t + 12];
        float2 w0 = __half22float2(Wb[(size_t)j0 * 64]);
        float2 w1 = __half22float2(Wb[(size_t)j1 * 64]);
        float2 w2 = __half22float2(Wb[(size_t)j2 * 64]);
        float2 w3 = __half22float2(Wb[(size_t)j3 * 64]);
        acc.x += q0 * w0.x + q1 * w1.x + q2 * w2.x + q3 * w3.x;
        acc.y += q0 * w0.y + q1 * w1.y + q2 * w2.y + q3 * w3.y;
    }
    for (; t < d; t += 4) {
        int j = s_idx[t]; float q = pk[t];
        float2 w = __half22float2(Wb[(size_t)j * 64]);
        acc.x += q * w.x; acc.y += q * w.y;
    }
    s_acc[tid] = acc;
    __syncthreads();
    if (tid < 64) {
        float2 v0 = s_acc[tid], v1 = s_acc[64 + tid],
               v2 = s_acc[128 + tid], v3 = s_acc[192 + tid];
        float inv = (tid & 32) ? inv1 : inv0;
        float2 r = { (v0.x + v1.x + v2.x + v3.x) * inv,
                     (v0.y + v1.y + v2.y + v3.y) * inv };
        ((__half2*)hI)[(size_t)i * 64 + tid] = __float22half2_rn(r);
    }
}

// ---- Kernel 3: out = relu(adj @ h'), via CSR; fp16 gather, fp32 out ---------
__global__ __launch_bounds__(256) void spmm_kernel(
    const __half* __restrict__ hI, const int* __restrict__ deg,
    const int* __restrict__ nbrs, float* __restrict__ out)
{
    __shared__ int   s_idx[MAXD];
    __shared__ float2 s_acc[256];
    int tid = threadIdx.x, i = blockIdx.x;
    int d = deg[i];
    if (tid < d) s_idx[tid] = nbrs[(size_t)i * MAXD + tid];
    __syncthreads();

    int grp = tid >> 6, h = tid & 63;
    const __half2* hb = (const __half2*)hI + h;
    float2 acc = {0.f, 0.f};
    int t = grp;
    for (; t + 12 < d; t += 16) {
        int j0 = s_idx[t], j1 = s_idx[t + 4], j2 = s_idx[t + 8], j3 = s_idx[t + 12];
        float2 w0 = __half22float2(hb[(size_t)j0 * 64]);
        float2 w1 = __half22float2(hb[(size_t)j1 * 64]);
        float2 w2 = __half22float2(hb[(size_t)j2 * 64]);
        float2 w3 = __half22float2(hb[(size_t)j3 * 64]);
        acc.x += w0.x + w1.x + w2.x + w3.x;
        acc.y += w0.y + w1.y + w2.y + w3.y;
    }
    for (; t < d; t += 4) {
        float2 w = __half22float2(hb[(size_t)s_idx[t] * 64]);
        acc.x += w.x; acc.y += w.y;
    }
    s_acc[tid] = acc;
    __syncthreads();
    if (tid < 64) {
        float2 v0 = s_acc[tid], v1 = s_acc[64 + tid],
               v2 = s_acc[128 + tid], v3 = s_acc[192 + tid];
        int k = tid >> 5;                  // 0 or 1
        float2 r = { fmaxf(v0.x + v1.x + v2.x + v3.x, 0.f),
                     fmaxf(v0.y + v1.y + v2.y + v3.y, 0.f) };
        ((float2*)(out + (size_t)k * NN * OUTF + (size_t)i * OUTF))[tid & 31] = r;
    }
}

extern "C" void kernel_launch(void* const* d_in, const int* in_sizes, int n_in,
                              void* d_out, int out_size, void* d_ws, size_t ws_size,
                              hipStream_t stream) {
    const float* x      = (const float*)d_in[0];   // [2, 8192, 128]
    const float* adj    = (const float*)d_in[1];   // [8192, 8192]
    const float* weight = (const float*)d_in[2];   // [128, 64]
    const float* a      = (const float*)d_in[3];   // [128, 1]
    float* out = (float*)d_out;                    // [2, 8192, 64] fp32

    // ws layout: WhI fp16 [N][128] (2 MB) | hI fp16 [N][128] (2 MB)
    //            Wh1 fp32 [2][N] | W2I fp32 [N][2] | deg [N] | nbrs [N][MAXD]
    __half* WhI = (__half*)d_ws;
    __half* hI  = WhI + (size_t)NN * 128;
    float*  Wh1 = (float*)(hI + (size_t)NN * 128);
    float*  W2I = Wh1 + NROWS;
    int*    deg = (int*)(W2I + (size_t)NN * KK);
    int*    nbrs = deg + NN;

    wh_kernel<<<NROWS / WH_RPB, 256, 0, stream>>>(x, weight, a, WhI, Wh1, W2I);
    attn_kernel<<<NN, 256, 0, stream>>>(adj, WhI, Wh1, W2I, hI, deg, nbrs);
    spmm_kernel<<<NN, 256, 0, stream>>>(hI, deg, nbrs, out);
}

// Round 5
// 388.345 us; speedup vs baseline: 1.2467x; 1.0551x over previous
//
#include <hip/hip_runtime.h>
#include <hip/hip_fp16.h>

#define NN 8192
#define INF 128
#define OUTF 64
#define KK 2
#define NROWS (KK * NN)
#define MAXD 256
#define WH_RPB 16

typedef float floatx4 __attribute__((ext_vector_type(4)));

// ---- Kernel 1: Wh = x@W -> WhI fp16 [j][k*64+f]; Wh1 fp32 [k][N]; W2I fp32 [j][k]
__global__ __launch_bounds__(256) void wh_kernel(
    const float* __restrict__ x, const float* __restrict__ weight,
    const float* __restrict__ a,
    __half* __restrict__ WhI, float* __restrict__ Wh1, float* __restrict__ W2I)
{
    __shared__ float sW[INF * OUTF];       // 32 KB
    __shared__ float sx[WH_RPB * INF];     // 8 KB
    int tid = threadIdx.x;
#pragma unroll
    for (int idx = tid; idx < (INF * OUTF) / 4; idx += 256)
        ((float4*)sW)[idx] = ((const float4*)weight)[idx];
    int rowBase = blockIdx.x * WH_RPB;     // global row in [0, 16384)
    const float4* xb = (const float4*)(x + (size_t)rowBase * INF);
#pragma unroll
    for (int idx = tid; idx < (WH_RPB * INF) / 4; idx += 256)
        ((float4*)sx)[idx] = xb[idx];
    __syncthreads();

    int wave = tid >> 6, lane = tid & 63;
    float a1 = a[lane], a2 = a[OUTF + lane];
    for (int r = wave; r < WH_RPB; r += 4) {
        float acc = 0.f;
#pragma unroll 16
        for (int c = 0; c < INF; ++c) acc += sx[r * INF + c] * sW[c * OUTF + lane];
        int g = rowBase + r;
        int k = g >> 13;                   // g / NN
        int j = g & (NN - 1);              // g % NN
        WhI[(size_t)j * 128 + k * OUTF + lane] = __float2half(acc);
        float w1 = acc * a1, w2 = acc * a2;
#pragma unroll
        for (int off = 32; off; off >>= 1) {
            w1 += __shfl_down(w1, off);
            w2 += __shfl_down(w2, off);
        }
        if (lane == 0) { Wh1[k * NN + j] = w1; W2I[j * KK + k] = w2; }
    }
}

// ---- Kernel 2: adj-row scan (prefix-sum compact) + sparse softmax + att@Wh --
__global__ __launch_bounds__(256) void attn_kernel(
    const float* __restrict__ adj, const __half* __restrict__ WhI,
    const float* __restrict__ Wh1, const float* __restrict__ W2I,
    __half* __restrict__ hI, int* __restrict__ deg, int* __restrict__ nbrs)
{
    __shared__ int   s_idx[MAXD];            // 1 KB
    __shared__ float s_p0[MAXD], s_p1[MAXD]; // 2 KB
    __shared__ float s_r0[4], s_r1[4];
    __shared__ int   s_wcnt[4];
    __shared__ float2 s_acc[256];            // 2 KB

    int tid = threadIdx.x;
    int i = blockIdx.x;
    int lane = tid & 63, wv = tid >> 6;

    // ---- Phase A: batched row read, register mask, prefix-sum compaction ----
    const floatx4* row4 = (const floatx4*)(adj + (size_t)i * NN);
    floatx4 v[8];
#pragma unroll
    for (int it = 0; it < 8; ++it)
        v[it] = __builtin_nontemporal_load(&row4[tid + it * 256]);
    unsigned int msk = 0;
#pragma unroll
    for (int it = 0; it < 8; ++it) {
        if (v[it].x > 0.f) msk |= 1u << (it * 4 + 0);
        if (v[it].y > 0.f) msk |= 1u << (it * 4 + 1);
        if (v[it].z > 0.f) msk |= 1u << (it * 4 + 2);
        if (v[it].w > 0.f) msk |= 1u << (it * 4 + 3);
    }
    int cnt = __popc(msk);
    int pre = cnt;                           // inclusive prefix within wave
#pragma unroll
    for (int off = 1; off < 64; off <<= 1) {
        int n = __shfl_up(pre, off);
        if (lane >= off) pre += n;
    }
    if (lane == 63) s_wcnt[wv] = pre;        // wave total
    __syncthreads();
    int base = 0;
#pragma unroll
    for (int w = 0; w < 4; ++w) if (w < wv) base += s_wcnt[w];
    int d = min(s_wcnt[0] + s_wcnt[1] + s_wcnt[2] + s_wcnt[3], MAXD);
    int pos = base + pre - cnt;              // exclusive offset for this thread
    while (msk) {
        int b = __ffs(msk) - 1;
        msk &= msk - 1;
        if (pos < MAXD) s_idx[pos] = (tid + (b >> 2) * 256) * 4 + (b & 3);
        ++pos;
    }
    __syncthreads();
    if (tid == 0) deg[i] = d;
    if (tid < d) nbrs[(size_t)i * MAXD + tid] = s_idx[tid];

    // ---- Phase B: e = relu(Wh1_i + Wh2_j), exact softmax (one thread per nbr)
    float wh1_0 = Wh1[i];
    float wh1_1 = Wh1[NN + i];
    float e0 = -1e30f, e1 = -1e30f;
    if (tid < d) {
        int j = s_idx[tid];
        float2 w2 = ((const float2*)W2I)[j];
        e0 = fmaxf(wh1_0 + w2.x, 0.f);
        e1 = fmaxf(wh1_1 + w2.y, 0.f);
    }
    float m0 = e0, m1 = e1;
#pragma unroll
    for (int off = 32; off; off >>= 1) {
        m0 = fmaxf(m0, __shfl_down(m0, off));
        m1 = fmaxf(m1, __shfl_down(m1, off));
    }
    if (lane == 0) { s_r0[wv] = m0; s_r1[wv] = m1; }
    __syncthreads();
    m0 = fmaxf(fmaxf(s_r0[0], s_r0[1]), fmaxf(s_r0[2], s_r0[3]));
    m1 = fmaxf(fmaxf(s_r1[0], s_r1[1]), fmaxf(s_r1[2], s_r1[3]));
    __syncthreads();                       // WAR on s_r
    float p0 = 0.f, p1 = 0.f;
    if (tid < d) {
        p0 = __expf(e0 - m0);
        p1 = __expf(e1 - m1);
        s_p0[tid] = p0; s_p1[tid] = p1;
    }
    float t0 = p0, t1 = p1;
#pragma unroll
    for (int off = 32; off; off >>= 1) {
        t0 += __shfl_down(t0, off);
        t1 += __shfl_down(t1, off);
    }
    if (lane == 0) { s_r0[wv] = t0; s_r1[wv] = t1; }
    __syncthreads();
    float sum0 = s_r0[0] + s_r0[1] + s_r0[2] + s_r0[3];
    float sum1 = s_r1[0] + s_r1[1] + s_r1[2] + s_r1[3];
    float inv0 = sum0 > 0.f ? 1.f / sum0 : 0.f;
    float inv1 = sum1 > 0.f ? 1.f / sum1 : 0.f;

    // ---- Phase C: h'[i, 2h..2h+1] = sum_t p[k][t] * WhI[j_t, 2h..2h+1]
    int grp = tid >> 6;                    // t-range split 4 ways
    int h = tid & 63;                      // half2 column; k = h>>5
    const float* pk = (h & 32) ? s_p1 : s_p0;
    const __half2* Wb = (const __half2*)WhI + h;
    float2 acc = {0.f, 0.f};
    int t = grp;
    for (; t + 12 < d; t += 16) {
        int j0 = s_idx[t], j1 = s_idx[t + 4], j2 = s_idx[t + 8], j3 = s_idx[t + 12];
        float q0 = pk[t], q1 = pk[t + 4], q2 = pk[t + 8], q3 = pk[t + 12];
        float2 w0 = __half22float2(Wb[(size_t)j0 * 64]);
        float2 w1 = __half22float2(Wb[(size_t)j1 * 64]);
        float2 w2 = __half22float2(Wb[(size_t)j2 * 64]);
        float2 w3 = __half22float2(Wb[(size_t)j3 * 64]);
        acc.x += q0 * w0.x + q1 * w1.x + q2 * w2.x + q3 * w3.x;
        acc.y += q0 * w0.y + q1 * w1.y + q2 * w2.y + q3 * w3.y;
    }
    for (; t < d; t += 4) {
        int j = s_idx[t]; float q = pk[t];
        float2 w = __half22float2(Wb[(size_t)j * 64]);
        acc.x += q * w.x; acc.y += q * w.y;
    }
    s_acc[tid] = acc;
    __syncthreads();
    if (tid < 64) {
        float2 v0 = s_acc[tid], v1 = s_acc[64 + tid],
               v2 = s_acc[128 + tid], v3 = s_acc[192 + tid];
        float inv = (tid & 32) ? inv1 : inv0;
        float2 r = { (v0.x + v1.x + v2.x + v3.x) * inv,
                     (v0.y + v1.y + v2.y + v3.y) * inv };
        ((__half2*)hI)[(size_t)i * 64 + tid] = __float22half2_rn(r);
    }
}

// ---- Kernel 3: out = relu(adj @ h'), via CSR; fp16 gather, fp32 out ---------
__global__ __launch_bounds__(256) void spmm_kernel(
    const __half* __restrict__ hI, const int* __restrict__ deg,
    const int* __restrict__ nbrs, float* __restrict__ out)
{
    __shared__ int   s_idx[MAXD];
    __shared__ float2 s_acc[256];
    int tid = threadIdx.x, i = blockIdx.x;
    int d = deg[i];
    if (tid < d) s_idx[tid] = nbrs[(size_t)i * MAXD + tid];
    __syncthreads();

    int grp = tid >> 6, h = tid & 63;
    const __half2* hb = (const __half2*)hI + h;
    float2 acc = {0.f, 0.f};
    int t = grp;
    for (; t + 12 < d; t += 16) {
        int j0 = s_idx[t], j1 = s_idx[t + 4], j2 = s_idx[t + 8], j3 = s_idx[t + 12];
        float2 w0 = __half22float2(hb[(size_t)j0 * 64]);
        float2 w1 = __half22float2(hb[(size_t)j1 * 64]);
        float2 w2 = __half22float2(hb[(size_t)j2 * 64]);
        float2 w3 = __half22float2(hb[(size_t)j3 * 64]);
        acc.x += w0.x + w1.x + w2.x + w3.x;
        acc.y += w0.y + w1.y + w2.y + w3.y;
    }
    for (; t < d; t += 4) {
        float2 w = __half22float2(hb[(size_t)s_idx[t] * 64]);
        acc.x += w.x; acc.y += w.y;
    }
    s_acc[tid] = acc;
    __syncthreads();
    if (tid < 64) {
        float2 v0 = s_acc[tid], v1 = s_acc[64 + tid],
               v2 = s_acc[128 + tid], v3 = s_acc[192 + tid];
        int k = tid >> 5;                  // 0 or 1
        float2 r = { fmaxf(v0.x + v1.x + v2.x + v3.x, 0.f),
                     fmaxf(v0.y + v1.y + v2.y + v3.y, 0.f) };
        ((float2*)(out + (size_t)k * NN * OUTF + (size_t)i * OUTF))[tid & 31] = r;
    }
}

extern "C" void kernel_launch(void* const* d_in, const int* in_sizes, int n_in,
                              void* d_out, int out_size, void* d_ws, size_t ws_size,
                              hipStream_t stream) {
    const float* x      = (const float*)d_in[0];   // [2, 8192, 128]
    const float* adj    = (const float*)d_in[1];   // [8192, 8192]
    const float* weight = (const float*)d_in[2];   // [128, 64]
    const float* a      = (const float*)d_in[3];   // [128, 1]
    float* out = (float*)d_out;                    // [2, 8192, 64] fp32

    // ws layout: WhI fp16 [N][128] (2 MB) | hI fp16 [N][128] (2 MB)
    //            Wh1 fp32 [2][N] | W2I fp32 [N][2] | deg [N] | nbrs [N][MAXD]
    __half* WhI = (__half*)d_ws;
    __half* hI  = WhI + (size_t)NN * 128;
    float*  Wh1 = (float*)(hI + (size_t)NN * 128);
    float*  W2I = Wh1 + NROWS;
    int*    deg = (int*)(W2I + (size_t)NN * KK);
    int*    nbrs = deg + NN;

    wh_kernel<<<NROWS / WH_RPB, 256, 0, stream>>>(x, weight, a, WhI, Wh1, W2I);
    attn_kernel<<<NN, 256, 0, stream>>>(adj, WhI, Wh1, W2I, hI, deg, nbrs);
    spmm_kernel<<<NN, 256, 0, stream>>>(hI, deg, nbrs, out);
}

// Round 6
// 385.016 us; speedup vs baseline: 1.2574x; 1.0086x over previous
//
#include <hip/hip_runtime.h>
#include <hip/hip_fp16.h>

#define NN 8192
#define INF 128
#define OUTF 64
#define KK 2
#define NROWS (KK * NN)
#define MAXD 256
#define WH_RPB 16

typedef float floatx4 __attribute__((ext_vector_type(4)));

// ---- Kernel 1: Wh = x@W -> WhI fp16 [j][k*64+f]; Wh1 fp32 [k][N]; W2I fp32 [j][k]
__global__ __launch_bounds__(256) void wh_kernel(
    const float* __restrict__ x, const float* __restrict__ weight,
    const float* __restrict__ a,
    __half* __restrict__ WhI, float* __restrict__ Wh1, float* __restrict__ W2I)
{
    __shared__ float sW[INF * OUTF];       // 32 KB
    __shared__ float sx[WH_RPB * INF];     // 8 KB
    int tid = threadIdx.x;
#pragma unroll
    for (int idx = tid; idx < (INF * OUTF) / 4; idx += 256)
        ((float4*)sW)[idx] = ((const float4*)weight)[idx];
    int rowBase = blockIdx.x * WH_RPB;     // global row in [0, 16384)
    const float4* xb = (const float4*)(x + (size_t)rowBase * INF);
#pragma unroll
    for (int idx = tid; idx < (WH_RPB * INF) / 4; idx += 256)
        ((float4*)sx)[idx] = xb[idx];
    __syncthreads();

    int wave = tid >> 6, lane = tid & 63;
    float a1 = a[lane], a2 = a[OUTF + lane];
    for (int r = wave; r < WH_RPB; r += 4) {
        float acc = 0.f;
#pragma unroll 16
        for (int c = 0; c < INF; ++c) acc += sx[r * INF + c] * sW[c * OUTF + lane];
        int g = rowBase + r;
        int k = g >> 13;                   // g / NN
        int j = g & (NN - 1);              // g % NN
        WhI[(size_t)j * 128 + k * OUTF + lane] = __float2half(acc);
        float w1 = acc * a1, w2 = acc * a2;
#pragma unroll
        for (int off = 32; off; off >>= 1) {
            w1 += __shfl_down(w1, off);
            w2 += __shfl_down(w2, off);
        }
        if (lane == 0) { Wh1[k * NN + j] = w1; W2I[j * KK + k] = w2; }
    }
}

// ---- Kernel 2: wave-per-row, barrier-free: scan+compact+softmax+gather ------
__global__ __launch_bounds__(256) void attn_kernel(
    const float* __restrict__ adj, const __half* __restrict__ WhI,
    const float* __restrict__ Wh1, const float* __restrict__ W2I,
    __half* __restrict__ hI, int* __restrict__ deg, int* __restrict__ nbrs)
{
    __shared__ int   s_idx[4][MAXD];          // 4 KB
    __shared__ float s_p0[4][MAXD];           // 4 KB
    __shared__ float s_p1[4][MAXD];           // 4 KB

    int tid = threadIdx.x, lane = tid & 63, wv = tid >> 6;
    int i = blockIdx.x * 4 + wv;
    const floatx4* row4 = (const floatx4*)(adj + (size_t)i * NN);

    // ---- Phase A: scan own row in 4 chunks of 8 dwordx4/lane, SW-pipelined
    floatx4 vA[8], vB[8];
#pragma unroll
    for (int it = 0; it < 8; ++it)
        vA[it] = __builtin_nontemporal_load(&row4[it * 64 + lane]);
    int base = 0;
#pragma unroll
    for (int c = 0; c < 4; ++c) {
        if (c < 3) {
#pragma unroll
            for (int it = 0; it < 8; ++it)
                vB[it] = __builtin_nontemporal_load(
                    &row4[(c + 1) * 512 + it * 64 + lane]);
        }
        unsigned int msk = 0;
#pragma unroll
        for (int it = 0; it < 8; ++it) {
            if (vA[it].x > 0.f) msk |= 1u << (it * 4 + 0);
            if (vA[it].y > 0.f) msk |= 1u << (it * 4 + 1);
            if (vA[it].z > 0.f) msk |= 1u << (it * 4 + 2);
            if (vA[it].w > 0.f) msk |= 1u << (it * 4 + 3);
        }
        int cnt = __popc(msk);
        int pre = cnt;                         // wave-inclusive prefix
#pragma unroll
        for (int off = 1; off < 64; off <<= 1) {
            int n = __shfl_up(pre, off);
            if (lane >= off) pre += n;
        }
        int tot = __shfl(pre, 63);
        int pos = base + pre - cnt;
        while (msk) {
            int b = __ffs(msk) - 1;
            msk &= msk - 1;
            if (pos < MAXD)
                s_idx[wv][pos] = (c * 512 + (b >> 2) * 64 + lane) * 4 + (b & 3);
            ++pos;
        }
        base += tot;
#pragma unroll
        for (int it = 0; it < 8; ++it) vA[it] = vB[it];
    }
    int d = min(base, MAXD);
    if (lane == 0) deg[i] = d;
    for (int t = lane; t < d; t += 64) nbrs[(size_t)i * MAXD + t] = s_idx[wv][t];

    // ---- Phase B: softmax over neighbors, wave-local (4 slots/lane) ----
    float wh1_0 = Wh1[i], wh1_1 = Wh1[NN + i];
    float e0[4], e1[4];
    float m0 = -1e30f, m1 = -1e30f;
#pragma unroll
    for (int s = 0; s < 4; ++s) {
        int t = lane + s * 64;
        e0[s] = -1e30f; e1[s] = -1e30f;
        if (t < d) {
            int j = s_idx[wv][t];
            float2 w2 = ((const float2*)W2I)[j];
            e0[s] = fmaxf(wh1_0 + w2.x, 0.f);
            e1[s] = fmaxf(wh1_1 + w2.y, 0.f);
        }
        m0 = fmaxf(m0, e0[s]); m1 = fmaxf(m1, e1[s]);
    }
#pragma unroll
    for (int off = 32; off; off >>= 1) {
        m0 = fmaxf(m0, __shfl_xor(m0, off));
        m1 = fmaxf(m1, __shfl_xor(m1, off));
    }
    float sum0 = 0.f, sum1 = 0.f;
#pragma unroll
    for (int s = 0; s < 4; ++s) {
        int t = lane + s * 64;
        if (t < d) {
            float p0 = __expf(e0[s] - m0), p1 = __expf(e1[s] - m1);
            s_p0[wv][t] = p0; s_p1[wv][t] = p1;
            sum0 += p0; sum1 += p1;
        }
    }
#pragma unroll
    for (int off = 32; off; off >>= 1) {
        sum0 += __shfl_xor(sum0, off);
        sum1 += __shfl_xor(sum1, off);
    }
    float inv0 = sum0 > 0.f ? 1.f / sum0 : 0.f;
    float inv1 = sum1 > 0.f ? 1.f / sum1 : 0.f;

    // ---- Phase C: h'[i, 2h..2h+1] = sum_t p[k][t] * WhI[j_t, 2h..2h+1] ----
    int h = lane;                              // half2 col; k = h>>5
    const float* pk = (h & 32) ? s_p1[wv] : s_p0[wv];
    const __half2* Wb = (const __half2*)WhI + h;
    float2 acc = {0.f, 0.f};
    int t = 0;
    for (; t + 7 < d; t += 8) {
        float2 w[8]; float q[8];
#pragma unroll
        for (int u = 0; u < 8; ++u) {
            int j = s_idx[wv][t + u];
            q[u] = pk[t + u];
            w[u] = __half22float2(Wb[(size_t)j * 64]);
        }
#pragma unroll
        for (int u = 0; u < 8; ++u) { acc.x += q[u] * w[u].x; acc.y += q[u] * w[u].y; }
    }
    for (; t < d; ++t) {
        float2 w = __half22float2(Wb[(size_t)s_idx[wv][t] * 64]);
        float q = pk[t];
        acc.x += q * w.x; acc.y += q * w.y;
    }
    float inv = (h & 32) ? inv1 : inv0;
    float2 r = { acc.x * inv, acc.y * inv };
    ((__half2*)hI)[(size_t)i * 64 + h] = __float22half2_rn(r);
}

// ---- Kernel 3: out = relu(adj @ h'), wave-per-row via CSR, barrier-free ----
__global__ __launch_bounds__(256) void spmm_kernel(
    const __half* __restrict__ hI, const int* __restrict__ deg,
    const int* __restrict__ nbrs, float* __restrict__ out)
{
    __shared__ int s_idx[4][MAXD];
    int tid = threadIdx.x, lane = tid & 63, wv = tid >> 6;
    int i = blockIdx.x * 4 + wv;
    int d = deg[i];
    for (int t = lane; t < d; t += 64) s_idx[wv][t] = nbrs[(size_t)i * MAXD + t];

    int h = lane;
    const __half2* hb = (const __half2*)hI + h;
    float2 acc = {0.f, 0.f};
    int t = 0;
    for (; t + 7 < d; t += 8) {
        float2 w[8];
#pragma unroll
        for (int u = 0; u < 8; ++u)
            w[u] = __half22float2(hb[(size_t)s_idx[wv][t + u] * 64]);
#pragma unroll
        for (int u = 0; u < 8; ++u) { acc.x += w[u].x; acc.y += w[u].y; }
    }
    for (; t < d; ++t) {
        float2 w = __half22float2(hb[(size_t)s_idx[wv][t] * 64]);
        acc.x += w.x; acc.y += w.y;
    }
    int k = h >> 5;
    float2 r = { fmaxf(acc.x, 0.f), fmaxf(acc.y, 0.f) };
    ((float2*)(out + ((size_t)k * NN + i) * OUTF))[h & 31] = r;
}

extern "C" void kernel_launch(void* const* d_in, const int* in_sizes, int n_in,
                              void* d_out, int out_size, void* d_ws, size_t ws_size,
                              hipStream_t stream) {
    const float* x      = (const float*)d_in[0];   // [2, 8192, 128]
    const float* adj    = (const float*)d_in[1];   // [8192, 8192]
    const float* weight = (const float*)d_in[2];   // [128, 64]
    const float* a      = (const float*)d_in[3];   // [128, 1]
    float* out = (float*)d_out;                    // [2, 8192, 64] fp32

    // ws layout: WhI fp16 [N][128] (2 MB) | hI fp16 [N][128] (2 MB)
    //            Wh1 fp32 [2][N] | W2I fp32 [N][2] | deg [N] | nbrs [N][MAXD]
    __half* WhI = (__half*)d_ws;
    __half* hI  = WhI + (size_t)NN * 128;
    float*  Wh1 = (float*)(hI + (size_t)NN * 128);
    float*  W2I = Wh1 + NROWS;
    int*    deg = (int*)(W2I + (size_t)NN * KK);
    int*    nbrs = deg + NN;

    wh_kernel<<<NROWS / WH_RPB, 256, 0, stream>>>(x, weight, a, WhI, Wh1, W2I);
    attn_kernel<<<NN / 4, 256, 0, stream>>>(adj, WhI, Wh1, W2I, hI, deg, nbrs);
    spmm_kernel<<<NN / 4, 256, 0, stream>>>(hI, deg, nbrs, out);
}

// Round 7
// 374.199 us; speedup vs baseline: 1.2938x; 1.0289x over previous
//
#include <hip/hip_runtime.h>
#include <hip/hip_fp16.h>

#define NN 8192
#define INF 128
#define OUTF 64
#define KK 2
#define NROWS (KK * NN)
#define MAXD 256
#define WH_RPB 16
#define WPAD 130

typedef float floatx4 __attribute__((ext_vector_type(4)));

// ---- Kernel 1: Wh = x@W -> WhI fp16 [j][k*64+f]; Wh1 fp32 [k][N]; W2I fp32 [j][k]
__global__ __launch_bounds__(256) void wh_kernel(
    const float* __restrict__ x, const float* __restrict__ weight,
    const float* __restrict__ a,
    __half* __restrict__ WhI, float* __restrict__ Wh1, float* __restrict__ W2I)
{
    __shared__ float sWt[OUTF * WPAD];     // transposed W: [f][c], pad 130 (33 KB)
    __shared__ float sx[WH_RPB * INF];     // 8 KB
    int tid = threadIdx.x;
    for (int idx = tid; idx < INF * OUTF; idx += 256) {
        int c = idx >> 6, f = idx & 63;    // weight[c][f] row-major [128][64]
        sWt[f * WPAD + c] = weight[idx];
    }
    int rowBase = blockIdx.x * WH_RPB;     // global row in [0, 16384)
    const float4* xb = (const float4*)(x + (size_t)rowBase * INF);
#pragma unroll
    for (int idx = tid; idx < (WH_RPB * INF) / 4; idx += 256)
        ((float4*)sx)[idx] = xb[idx];
    __syncthreads();

    int wave = tid >> 6, lane = tid & 63;
    float a1 = a[lane], a2 = a[OUTF + lane];
    const float* wrow = &sWt[lane * WPAD]; // lane's own contiguous weight row
    for (int r = wave; r < WH_RPB; r += 4) {
        const float4* sx4 = (const float4*)&sx[r * INF];
        float acc = 0.f;
#pragma unroll
        for (int c4 = 0; c4 < INF / 4; ++c4) {
            float4 xv = sx4[c4];
            acc += xv.x * wrow[c4 * 4 + 0] + xv.y * wrow[c4 * 4 + 1]
                 + xv.z * wrow[c4 * 4 + 2] + xv.w * wrow[c4 * 4 + 3];
        }
        int g = rowBase + r;
        int k = g >> 13;                   // g / NN
        int j = g & (NN - 1);              // g % NN
        // reductions + pairing shuffles while exec is full
        float w1 = acc * a1, w2 = acc * a2;
#pragma unroll
        for (int off = 32; off; off >>= 1) {
            w1 += __shfl_down(w1, off);
            w2 += __shfl_down(w2, off);
        }
        float other = __shfl_xor(acc, 1);  // f=lane^1 partner
        if ((lane & 1) == 0) {
            __half2 hv = __halves2half2(__float2half(acc), __float2half(other));
            ((__half2*)(WhI + (size_t)j * 128 + k * OUTF))[lane >> 1] = hv;
        }
        if (lane == 0) { Wh1[k * NN + j] = w1; W2I[j * KK + k] = w2; }
    }
}

// ---- Kernel 2: wave-per-row, barrier-free: scan+compact+softmax+gather ------
__global__ __launch_bounds__(256) void attn_kernel(
    const float* __restrict__ adj, const __half* __restrict__ WhI,
    const float* __restrict__ Wh1, const float* __restrict__ W2I,
    __half* __restrict__ hI, int* __restrict__ deg, int* __restrict__ nbrs)
{
    __shared__ int   s_idx[4][MAXD];          // 4 KB
    __shared__ float s_p0[4][MAXD];           // 4 KB
    __shared__ float s_p1[4][MAXD];           // 4 KB

    int tid = threadIdx.x, lane = tid & 63, wv = tid >> 6;
    int i = blockIdx.x * 4 + wv;
    const floatx4* row4 = (const floatx4*)(adj + (size_t)i * NN);

    // ---- Phase A: scan own row in 4 chunks of 8 dwordx4/lane, SW-pipelined
    floatx4 vA[8], vB[8];
#pragma unroll
    for (int it = 0; it < 8; ++it)
        vA[it] = __builtin_nontemporal_load(&row4[it * 64 + lane]);
    int base = 0;
#pragma unroll
    for (int c = 0; c < 4; ++c) {
        if (c < 3) {
#pragma unroll
            for (int it = 0; it < 8; ++it)
                vB[it] = __builtin_nontemporal_load(
                    &row4[(c + 1) * 512 + it * 64 + lane]);
        }
        unsigned int msk = 0;
#pragma unroll
        for (int it = 0; it < 8; ++it) {
            if (vA[it].x > 0.f) msk |= 1u << (it * 4 + 0);
            if (vA[it].y > 0.f) msk |= 1u << (it * 4 + 1);
            if (vA[it].z > 0.f) msk |= 1u << (it * 4 + 2);
            if (vA[it].w > 0.f) msk |= 1u << (it * 4 + 3);
        }
        int cnt = __popc(msk);
        int pre = cnt;                         // wave-inclusive prefix
#pragma unroll
        for (int off = 1; off < 64; off <<= 1) {
            int n = __shfl_up(pre, off);
            if (lane >= off) pre += n;
        }
        int tot = __shfl(pre, 63);
        int pos = base + pre - cnt;
        while (msk) {
            int b = __ffs(msk) - 1;
            msk &= msk - 1;
            if (pos < MAXD)
                s_idx[wv][pos] = (c * 512 + (b >> 2) * 64 + lane) * 4 + (b & 3);
            ++pos;
        }
        base += tot;
#pragma unroll
        for (int it = 0; it < 8; ++it) vA[it] = vB[it];
    }
    int d = min(base, MAXD);
    if (lane == 0) deg[i] = d;
    for (int t = lane; t < d; t += 64) nbrs[(size_t)i * MAXD + t] = s_idx[wv][t];

    // ---- Phase B: softmax over neighbors, wave-local (4 slots/lane) ----
    float wh1_0 = Wh1[i], wh1_1 = Wh1[NN + i];
    float e0[4], e1[4];
    float m0 = -1e30f, m1 = -1e30f;
#pragma unroll
    for (int s = 0; s < 4; ++s) {
        int t = lane + s * 64;
        e0[s] = -1e30f; e1[s] = -1e30f;
        if (t < d) {
            int j = s_idx[wv][t];
            float2 w2 = ((const float2*)W2I)[j];
            e0[s] = fmaxf(wh1_0 + w2.x, 0.f);
            e1[s] = fmaxf(wh1_1 + w2.y, 0.f);
        }
        m0 = fmaxf(m0, e0[s]); m1 = fmaxf(m1, e1[s]);
    }
#pragma unroll
    for (int off = 32; off; off >>= 1) {
        m0 = fmaxf(m0, __shfl_xor(m0, off));
        m1 = fmaxf(m1, __shfl_xor(m1, off));
    }
    float sum0 = 0.f, sum1 = 0.f;
#pragma unroll
    for (int s = 0; s < 4; ++s) {
        int t = lane + s * 64;
        if (t < d) {
            float p0 = __expf(e0[s] - m0), p1 = __expf(e1[s] - m1);
            s_p0[wv][t] = p0; s_p1[wv][t] = p1;
            sum0 += p0; sum1 += p1;
        }
    }
#pragma unroll
    for (int off = 32; off; off >>= 1) {
        sum0 += __shfl_xor(sum0, off);
        sum1 += __shfl_xor(sum1, off);
    }
    float inv0 = sum0 > 0.f ? 1.f / sum0 : 0.f;
    float inv1 = sum1 > 0.f ? 1.f / sum1 : 0.f;

    // ---- Phase C: h'[i, 2h..2h+1] = sum_t p[k][t] * WhI[j_t, 2h..2h+1] ----
    int h = lane;                              // half2 col; k = h>>5
    const float* pk = (h & 32) ? s_p1[wv] : s_p0[wv];
    const __half2* Wb = (const __half2*)WhI + h;
    float2 acc = {0.f, 0.f};
    int t = 0;
    for (; t + 15 < d; t += 16) {
        int jj[16]; float q[16]; float2 w[16];
#pragma unroll
        for (int u = 0; u < 16; ++u) { jj[u] = s_idx[wv][t + u]; q[u] = pk[t + u]; }
#pragma unroll
        for (int u = 0; u < 16; ++u) w[u] = __half22float2(Wb[(size_t)jj[u] * 64]);
#pragma unroll
        for (int u = 0; u < 16; ++u) { acc.x += q[u] * w[u].x; acc.y += q[u] * w[u].y; }
    }
    for (; t + 3 < d; t += 4) {
        int jj[4]; float q[4]; float2 w[4];
#pragma unroll
        for (int u = 0; u < 4; ++u) { jj[u] = s_idx[wv][t + u]; q[u] = pk[t + u]; }
#pragma unroll
        for (int u = 0; u < 4; ++u) w[u] = __half22float2(Wb[(size_t)jj[u] * 64]);
#pragma unroll
        for (int u = 0; u < 4; ++u) { acc.x += q[u] * w[u].x; acc.y += q[u] * w[u].y; }
    }
    for (; t < d; ++t) {
        float2 w = __half22float2(Wb[(size_t)s_idx[wv][t] * 64]);
        float q = pk[t];
        acc.x += q * w.x; acc.y += q * w.y;
    }
    float inv = (h & 32) ? inv1 : inv0;
    float2 r = { acc.x * inv, acc.y * inv };
    ((__half2*)hI)[(size_t)i * 64 + h] = __float22half2_rn(r);
}

// ---- Kernel 3: out = relu(adj @ h'), wave-per-row via CSR, barrier-free ----
__global__ __launch_bounds__(256) void spmm_kernel(
    const __half* __restrict__ hI, const int* __restrict__ deg,
    const int* __restrict__ nbrs, float* __restrict__ out)
{
    __shared__ int s_idx[4][MAXD];
    int tid = threadIdx.x, lane = tid & 63, wv = tid >> 6;
    int i = blockIdx.x * 4 + wv;
    int d = deg[i];
    for (int t = lane; t < d; t += 64) s_idx[wv][t] = nbrs[(size_t)i * MAXD + t];

    int h = lane;
    const __half2* hb = (const __half2*)hI + h;
    float2 acc = {0.f, 0.f};
    int t = 0;
    for (; t + 15 < d; t += 16) {
        int jj[16]; float2 w[16];
#pragma unroll
        for (int u = 0; u < 16; ++u) jj[u] = s_idx[wv][t + u];
#pragma unroll
        for (int u = 0; u < 16; ++u) w[u] = __half22float2(hb[(size_t)jj[u] * 64]);
#pragma unroll
        for (int u = 0; u < 16; ++u) { acc.x += w[u].x; acc.y += w[u].y; }
    }
    for (; t < d; ++t) {
        float2 w = __half22float2(hb[(size_t)s_idx[wv][t] * 64]);
        acc.x += w.x; acc.y += w.y;
    }
    int k = h >> 5;
    float2 r = { fmaxf(acc.x, 0.f), fmaxf(acc.y, 0.f) };
    ((float2*)(out + ((size_t)k * NN + i) * OUTF))[h & 31] = r;
}

extern "C" void kernel_launch(void* const* d_in, const int* in_sizes, int n_in,
                              void* d_out, int out_size, void* d_ws, size_t ws_size,
                              hipStream_t stream) {
    const float* x      = (const float*)d_in[0];   // [2, 8192, 128]
    const float* adj    = (const float*)d_in[1];   // [8192, 8192]
    const float* weight = (const float*)d_in[2];   // [128, 64]
    const float* a      = (const float*)d_in[3];   // [128, 1]
    float* out = (float*)d_out;                    // [2, 8192, 64] fp32

    // ws layout: WhI fp16 [N][128] (2 MB) | hI fp16 [N][128] (2 MB)
    //            Wh1 fp32 [2][N] | W2I fp32 [N][2] | deg [N] | nbrs [N][MAXD]
    __half* WhI = (__half*)d_ws;
    __half* hI  = WhI + (size_t)NN * 128;
    float*  Wh1 = (float*)(hI + (size_t)NN * 128);
    float*  W2I = Wh1 + NROWS;
    int*    deg = (int*)(W2I + (size_t)NN * KK);
    int*    nbrs = deg + NN;

    wh_kernel<<<NROWS / WH_RPB, 256, 0, stream>>>(x, weight, a, WhI, Wh1, W2I);
    attn_kernel<<<NN / 4, 256, 0, stream>>>(adj, WhI, Wh1, W2I, hI, deg, nbrs);
    spmm_kernel<<<NN / 4, 256, 0, stream>>>(hI, deg, nbrs, out);
}